// Round 1
// baseline (304.454 us; speedup 1.0000x reference)
//
#include <hip/hip_runtime.h>

// QuantilePreprocessing: per-feature searchsorted(1000 sorted quantiles) +
// linear interp + probit(y)=sqrt(2)*erfinv(2y-1), clamped to [-100,100].
// x: [256,4096,32] f32 (row-major, feature fastest), quantiles: [1000,32] f32.
//
// Strategy: quantiles + a 512-cell bracket table live in LDS (160,960 B,
// 1 block/CU, 1024 thr = 16 waves). XOR bank swizzle on the quantile layout
// breaks the "same feature -> same bank" 8-way conflict. Grid table turns the
// 10-probe binary search into ~5 predicated probes. Each thread owns a
// float4 of features -> 4 interleaved searches for LDS-latency ILP.

#define QN 1000
#define NF 32
#define G_CELLS 512                 // cells over [-4,4], h = 1/64 (exact fp32 edges)
#define NT (G_CELLS + 3)            // 515 table entries per feature (sentinels 0 / 1000)
#define LDS_Q_BYTES (QN * NF * 4)   // 128000
#define LDS_TB_BYTES (NT * NF * 2)  // 32960
#define LDS_TOTAL (LDS_Q_BYTES + LDS_TB_BYTES)  // 160960 <= 163840

__device__ __forceinline__ int qoff(int mid, int f) {
  // bank = f ^ (mid&31): spreads same-feature lanes across banks
  return (mid << 5) + (f ^ (mid & 31));
}
__device__ __forceinline__ int toff(int c, int f) {
  return (c << 5) + (f ^ (c & 31));
}

__device__ __forceinline__ float probit100(float y) {
  // clip(sqrt(2)*erfinv(2y-1), -100, 100), y in [0,1]
  if (y <= 0.0f) return -100.0f;   // exact tail: ref gives clip(-inf) = -100
  if (y >= 1.0f) return 100.0f;
  float t = 4.0f * y * (1.0f - y); // == (1-x)(1+x), no cancellation at tiny y
  float s = 2.0f * y - 1.0f;
  float w = -__logf(t);
  float p;
  if (w < 5.0f) {
    float u = w - 2.5f;
    p = 2.81022636e-08f;
    p = fmaf(p, u, 3.43273939e-07f);
    p = fmaf(p, u, -3.5233877e-06f);
    p = fmaf(p, u, -4.39150654e-06f);
    p = fmaf(p, u, 0.00021858087f);
    p = fmaf(p, u, -0.00125372503f);
    p = fmaf(p, u, -0.00417768164f);
    p = fmaf(p, u, 0.246640727f);
    p = fmaf(p, u, 1.50140941f);
  } else {
    // clamp keeps poly in its fit range and absorbs w=inf (FTZ'd t) safely
    float u = fminf(sqrtf(w) - 3.0f, 2.1f);
    p = -0.000200214257f;
    p = fmaf(p, u, 0.000100950558f);
    p = fmaf(p, u, 0.00134934322f);
    p = fmaf(p, u, -0.00367342844f);
    p = fmaf(p, u, 0.00573950773f);
    p = fmaf(p, u, -0.0076224613f);
    p = fmaf(p, u, 0.00943887047f);
    p = fmaf(p, u, 1.00167406f);
    p = fmaf(p, u, 2.83297682f);
  }
  float r = 1.41421356237f * p * s;
  return fminf(fmaxf(r, -100.0f), 100.0f);
}

__global__ __launch_bounds__(1024, 4) void qp_kernel(
    const float* __restrict__ x, const float* __restrict__ q,
    float* __restrict__ out, int nrows) {
  extern __shared__ char smem[];
  float* qs = (float*)smem;
  unsigned short* tb = (unsigned short*)(smem + LDS_Q_BYTES);
  const int t = threadIdx.x;

  // ---- stage quantiles (coalesced global, conflict-free LDS writes) ----
  for (int i = t; i < QN * NF; i += 1024) {
    int mid = i >> 5, f = i & 31;
    qs[qoff(mid, f)] = q[i];
  }
  __syncthreads();

  // ---- build bracket table: Tx[0]=0; Tx[c]=#{q < v_{c-1}}; Tx[NT-1]=1000 ----
  // v_k = -4 + k/64, exact in fp32 -> lookup floor() can only err +1 cell,
  // which the -1-cell widen at lookup time absorbs.
  for (int k = t; k < NT * NF; k += 1024) {
    int c = k >> 5, f = k & 31;
    unsigned short val;
    if (c == 0) {
      val = 0;
    } else if (c == NT - 1) {
      val = (unsigned short)QN;
    } else {
      float v = -4.0f + (float)(c - 1) * 0.015625f;  // exact
      int lo = 0, hi = QN;
      while (lo < hi) {
        int mid = (lo + hi) >> 1;
        if (qs[qoff(mid, f)] < v) lo = mid + 1; else hi = mid;
      }
      val = (unsigned short)lo;
    }
    tb[toff(c, f)] = val;
  }
  __syncthreads();

  // ---- main loop: thread owns 4 consecutive features of one row ----
  const int c8 = t & 7;        // feature quad 0..7
  const int rowo = t >> 3;     // 0..127 rows per block-iter
  const int f0 = c8 << 2;
  const int iters = nrows >> 7;  // 128 rows per iter

  int it = blockIdx.x;
  float4 xv = make_float4(0.f, 0.f, 0.f, 0.f);
  if (it < iters) {
    int row = (it << 7) + rowo;
    xv = *(const float4*)(x + ((size_t)row << 5) + f0);
  }
  while (it < iters) {
    int itn = it + gridDim.x;
    float4 xn = xv;
    if (itn < iters) {  // uniform branch; prefetch next tile
      int rown = (itn << 7) + rowo;
      xn = *(const float4*)(x + ((size_t)rown << 5) + f0);
    }

    float xa[4] = {xv.x, xv.y, xv.z, xv.w};
    int blo[4], bhi[4];

    // bracket lookup (widened one cell down)
#pragma unroll
    for (int j = 0; j < 4; j++) {
      int f = f0 + j;
      int cg = (int)floorf((xa[j] + 4.0f) * 64.0f);
      cg = max(min(cg, G_CELLS), -1) + 1;  // [0, 513]
      int cl = max(cg - 1, 0);
      blo[j] = tb[toff(cl, f)];
      bhi[j] = tb[toff(cg + 1, f)];
    }

    // 5 predicated binary-search steps, 4 searches interleaved
#pragma unroll
    for (int s = 0; s < 5; s++) {
#pragma unroll
      for (int j = 0; j < 4; j++) {
        int f = f0 + j;
        int lo = blo[j], hi = bhi[j];
        int mid = (lo + hi) >> 1;          // mid <= 1000, LDS read stays in-bounds
        float qm = qs[qoff(mid, f)];
        bool go = lo < hi;
        bool less = qm < xa[j];
        blo[j] = (go && less) ? mid + 1 : lo;
        bhi[j] = (go && !less) ? mid : hi;
      }
    }

    float res[4];
#pragma unroll
    for (int j = 0; j < 4; j++) {
      int f = f0 + j;
      // rare residual (bracket content > 31)
      while (blo[j] < bhi[j]) {
        int mid = (blo[j] + bhi[j]) >> 1;
        if (qs[qoff(mid, f)] < xa[j]) blo[j] = mid + 1; else bhi[j] = mid;
      }
      int cnt = blo[j];                       // searchsorted left
      int idx = min(max(cnt, 1), QN - 1) - 1; // 0..998
      float lo = qs[qoff(idx, f)];
      float hi = qs[qoff(idx + 1, f)];
      float diff = hi - lo;
      float interp = (diff == 0.0f) ? 0.5f : __fdividef(xa[j] - lo, diff);
      float y = ((float)idx + interp) * 0.001f;
      y = fminf(fmaxf(y, 0.0f), 1.0f);
      res[j] = probit100(y);
    }

    int row = (it << 7) + rowo;
    float4 ov = make_float4(res[0], res[1], res[2], res[3]);
    *(float4*)(out + ((size_t)row << 5) + f0) = ov;

    xv = xn;
    it = itn;
  }
}

extern "C" void kernel_launch(void* const* d_in, const int* in_sizes, int n_in,
                              void* d_out, int out_size, void* d_ws, size_t ws_size,
                              hipStream_t stream) {
  const float* x = (const float*)d_in[0];
  const float* q = (const float*)d_in[1];
  float* out = (float*)d_out;
  int n = in_sizes[0];         // 33,554,432
  int nrows = n / NF;          // 1,048,576 (divisible by 128)

  // opt-in to >64KB dynamic LDS (capture-safe: not a stream op)
  hipFuncSetAttribute((const void*)qp_kernel,
                      hipFuncAttributeMaxDynamicSharedMemorySize, LDS_TOTAL);

  qp_kernel<<<dim3(256), dim3(1024), LDS_TOTAL, stream>>>(x, q, out, nrows);
}

// Round 2
// 238.556 us; speedup vs baseline: 1.2762x; 1.2762x over previous
//
#include <hip/hip_runtime.h>

// QuantilePreprocessing via direct tabulation of the composite per-feature
// function g_f(x) = clip(probit(clip((idx+interp)/1000)), -100, 100).
// Error budget is 2.0 absolute; table lerp worst-case ~1.0 (analyzed), with
// the two true discontinuities (x<=q0 -> -100, y>=1 -> +100) handled exactly.
//
// Kernel 1 (build): 36,960 threads compute exact node values (round-1 math,
// quantiles L2-resident) into d_ws.
// Kernel 2 (main): stage 147,840 B of tables into LDS (1 block/CU, 16 waves),
// then stream x: region-select among {left-tail, middle, right-tail} tables,
// one ds_read2-pair lerp per element. No probit, no search in the hot loop.

#define QN 1000
#define NF 32
#define MID_N 641                    // 640 cells over [q1, q998]
#define TL_N 257                     // 256 cells per tail table
#define TBL_FLOATS (MID_N*NF + 2*TL_N*NF)   // 20512 + 16448 = 36960
#define TBL_BYTES (TBL_FLOATS * 4)          // 147,840 <= 163,840

__device__ __forceinline__ float probit100(float y) {
  // clip(sqrt(2)*erfinv(2y-1), -100, 100), y in [0,1]
  if (y <= 0.0f) return -100.0f;
  if (y >= 1.0f) return 100.0f;
  float t = 4.0f * y * (1.0f - y);
  float s = 2.0f * y - 1.0f;
  float w = -__logf(t);
  float p;
  if (w < 5.0f) {
    float u = w - 2.5f;
    p = 2.81022636e-08f;
    p = fmaf(p, u, 3.43273939e-07f);
    p = fmaf(p, u, -3.5233877e-06f);
    p = fmaf(p, u, -4.39150654e-06f);
    p = fmaf(p, u, 0.00021858087f);
    p = fmaf(p, u, -0.00125372503f);
    p = fmaf(p, u, -0.00417768164f);
    p = fmaf(p, u, 0.246640727f);
    p = fmaf(p, u, 1.50140941f);
  } else {
    float u = fminf(sqrtf(w) - 3.0f, 2.1f);
    p = -0.000200214257f;
    p = fmaf(p, u, 0.000100950558f);
    p = fmaf(p, u, 0.00134934322f);
    p = fmaf(p, u, -0.00367342844f);
    p = fmaf(p, u, 0.00573950773f);
    p = fmaf(p, u, -0.0076224613f);
    p = fmaf(p, u, 0.00943887047f);
    p = fmaf(p, u, 1.00167406f);
    p = fmaf(p, u, 2.83297682f);
  }
  float r = 1.41421356237f * p * s;
  return fminf(fmaxf(r, -100.0f), 100.0f);
}

// Exact reference pipeline for one value v, feature f (quantiles in global).
__device__ float eval_node(const float* __restrict__ q, int f, float v) {
  int lo = 0, hi = QN;
  while (lo < hi) {
    int mid = (lo + hi) >> 1;
    if (q[mid * 32 + f] < v) lo = mid + 1; else hi = mid;
  }
  int idx = min(max(lo, 1), QN - 1) - 1;
  float a = q[idx * 32 + f], b = q[(idx + 1) * 32 + f];
  float diff = b - a;
  float safe = (diff == 0.0f) ? 1.0f : diff;
  float interp = (diff == 0.0f) ? 0.5f : (v - a) / safe;
  float y = ((float)idx + interp) / 1000.0f;
  y = fminf(fmaxf(y, 0.0f), 1.0f);
  return probit100(y);
}

__global__ void build_kernel(const float* __restrict__ q, float* __restrict__ tbl) {
  int id = blockIdx.x * 256 + threadIdx.x;
  if (id >= TBL_FLOATS) return;
  int f = id & 31, slot = id >> 5;
  float qa = q[f];                 // q[0][f]
  float q1 = q[32 + f];            // q[1][f]
  float q8 = q[998 * 32 + f];      // q[998][f]
  float q9 = q[999 * 32 + f];      // q[999][f]
  float pos; int outIdx;
  if (slot < MID_N) {
    float h = (q8 - q1) * (1.0f / 640.0f);
    pos = q1 + (float)slot * h;
    outIdx = f * MID_N + slot;
  } else if (slot < MID_N + TL_N) {
    int n = slot - MID_N;
    float h = (q1 - qa) * (1.0f / 256.0f);
    // node 0 evaluated at h/16 inset: g(q0) = -100 would poison cell-0 chord
    float nn = (n == 0) ? 0.0625f : (float)n;
    pos = qa + nn * h;
    outIdx = NF * MID_N + f * TL_N + n;
  } else {
    int n = slot - MID_N - TL_N;
    float d = q9 - q8;
    float h = d * (2.0f / 256.0f);   // span [q998, q998 + 2*diff999]
    // last node inset by h/16: g(x_sat) = +100 would poison the last chord
    float nn = (n == TL_N - 1) ? 255.9375f : (float)n;
    pos = q8 + nn * h;
    outIdx = NF * MID_N + NF * TL_N + f * TL_N + n;
  }
  tbl[outIdx] = eval_node(q, f, pos);
}

__global__ __launch_bounds__(1024, 4) void qp_main(
    const float* __restrict__ x, const float* __restrict__ q,
    const float* __restrict__ tbl, float* __restrict__ out, int nrows) {
  extern __shared__ float lds[];
  const int t = threadIdx.x;

  // ---- stage tables global -> LDS, coalesced float4 ----
  {
    const float4* tg = (const float4*)tbl;
    float4* l4 = (float4*)lds;
    for (int i = t; i < TBL_FLOATS / 4; i += 1024) l4[i] = tg[i];
  }
  __syncthreads();

  // ---- per-feature params in registers (this thread's 4 features) ----
  const int c8 = t & 7, rowo = t >> 3, f0 = c8 << 2;
  float qa[4], q1f[4], q98[4], qz[4], dif9[4], l_inv[4], m_inv[4], r_inv[4];
  int mb[4], lb[4], rb[4];
#pragma unroll
  for (int j = 0; j < 4; j++) {
    int f = f0 + j;
    qa[j]  = q[f];
    q1f[j] = q[32 + f];
    q98[j] = q[998 * 32 + f];
    qz[j]  = q[999 * 32 + f];
    float d = qz[j] - q98[j];
    dif9[j]  = d;
    m_inv[j] = 640.0f / (q98[j] - q1f[j]);
    l_inv[j] = 256.0f / (q1f[j] - qa[j]);
    r_inv[j] = 128.0f / d;          // inf if d==0 (prob 0; sat path replicates ref)
    mb[j] = f * MID_N;
    lb[j] = NF * MID_N + f * TL_N;
    rb[j] = NF * MID_N + NF * TL_N + f * TL_N;
  }

  const int iters = nrows >> 7;     // 128 rows per block-iter
  int it = blockIdx.x;
  float4 xv = make_float4(0.f, 0.f, 0.f, 0.f);
  if (it < iters) {
    int row = (it << 7) + rowo;
    xv = *(const float4*)(x + ((size_t)row << 5) + f0);
  }
  while (it < iters) {
    int itn = it + gridDim.x;
    float4 xn = xv;
    if (itn < iters) {              // uniform prefetch of next tile
      int rown = (itn << 7) + rowo;
      xn = *(const float4*)(x + ((size_t)rown << 5) + f0);
    }

    float xa[4] = {xv.x, xv.y, xv.z, xv.w};
    float res[4];
#pragma unroll
    for (int j = 0; j < 4; j++) {
      float xj = xa[j];
      bool inL = xj < q1f[j];
      bool inR = xj > q98[j];
      float org = inL ? qa[j]   : (inR ? q98[j]   : q1f[j]);
      float inv = inL ? l_inv[j] : (inR ? r_inv[j] : m_inv[j]);
      int   bas = inL ? lb[j]   : (inR ? rb[j]    : mb[j]);
      int  ncm1 = (inL || inR) ? (TL_N - 2) : (MID_N - 2);
      float u = (xj - org) * inv;
      int i = (int)u;               // trunc toward 0; u>=0 whenever in-region
      i = min(i, ncm1);
      i = max(i, 0);
      float frac = u - (float)i;
      float T0 = lds[bas + i];
      float T1 = lds[bas + i + 1];  // ds_read2_b32 pair
      float val = fmaf(frac, T1 - T0, T0);
      // exact +100 saturation: only reachable when cnt==1000 i.e. x > q999.
      // Replicates ref f32 chain; (998+interp)>=1000 <=> y>=1 after f32 div.
      if (xj > qz[j]) {
        float d = dif9[j];
        float safe = (d == 0.0f) ? 1.0f : d;
        float interp = (d == 0.0f) ? 0.5f : (xj - q98[j]) / safe;
        if (998.0f + interp >= 1000.0f) val = 100.0f;
      }
      // exact -100 tail: cnt==0 <=> x <= q0 (compares two loaded f32s, bit-exact)
      val = (xj <= qa[j]) ? -100.0f : val;
      res[j] = val;
    }

    int row = (it << 7) + rowo;
    *(float4*)(out + ((size_t)row << 5) + f0) =
        make_float4(res[0], res[1], res[2], res[3]);

    xv = xn;
    it = itn;
  }
}

// ======================= round-1 fallback (ws too small) ====================
#define G_CELLS 512
#define NT (G_CELLS + 3)
#define LDS_Q_BYTES (QN * NF * 4)
#define LDS_TB_BYTES (NT * NF * 2)
#define LDS_TOTAL (LDS_Q_BYTES + LDS_TB_BYTES)

__device__ __forceinline__ int qoff(int mid, int f) {
  return (mid << 5) + (f ^ (mid & 31));
}
__device__ __forceinline__ int toff(int c, int f) {
  return (c << 5) + (f ^ (c & 31));
}

__global__ __launch_bounds__(1024, 4) void qp_kernel(
    const float* __restrict__ x, const float* __restrict__ q,
    float* __restrict__ out, int nrows) {
  extern __shared__ char smem[];
  float* qs = (float*)smem;
  unsigned short* tb = (unsigned short*)(smem + LDS_Q_BYTES);
  const int t = threadIdx.x;
  for (int i = t; i < QN * NF; i += 1024) {
    int mid = i >> 5, f = i & 31;
    qs[qoff(mid, f)] = q[i];
  }
  __syncthreads();
  for (int k = t; k < NT * NF; k += 1024) {
    int c = k >> 5, f = k & 31;
    unsigned short val;
    if (c == 0) val = 0;
    else if (c == NT - 1) val = (unsigned short)QN;
    else {
      float v = -4.0f + (float)(c - 1) * 0.015625f;
      int lo = 0, hi = QN;
      while (lo < hi) {
        int mid = (lo + hi) >> 1;
        if (qs[qoff(mid, f)] < v) lo = mid + 1; else hi = mid;
      }
      val = (unsigned short)lo;
    }
    tb[toff(c, f)] = val;
  }
  __syncthreads();
  const int c8 = t & 7, rowo = t >> 3, f0 = c8 << 2;
  const int iters = nrows >> 7;
  int it = blockIdx.x;
  float4 xv = make_float4(0.f, 0.f, 0.f, 0.f);
  if (it < iters) {
    int row = (it << 7) + rowo;
    xv = *(const float4*)(x + ((size_t)row << 5) + f0);
  }
  while (it < iters) {
    int itn = it + gridDim.x;
    float4 xn = xv;
    if (itn < iters) {
      int rown = (itn << 7) + rowo;
      xn = *(const float4*)(x + ((size_t)rown << 5) + f0);
    }
    float xa[4] = {xv.x, xv.y, xv.z, xv.w};
    int blo[4], bhi[4];
#pragma unroll
    for (int j = 0; j < 4; j++) {
      int f = f0 + j;
      int cg = (int)floorf((xa[j] + 4.0f) * 64.0f);
      cg = max(min(cg, G_CELLS), -1) + 1;
      int cl = max(cg - 1, 0);
      blo[j] = tb[toff(cl, f)];
      bhi[j] = tb[toff(cg + 1, f)];
    }
#pragma unroll
    for (int s = 0; s < 5; s++) {
#pragma unroll
      for (int j = 0; j < 4; j++) {
        int f = f0 + j;
        int lo = blo[j], hi = bhi[j];
        int mid = (lo + hi) >> 1;
        float qm = qs[qoff(mid, f)];
        bool go = lo < hi;
        bool less = qm < xa[j];
        blo[j] = (go && less) ? mid + 1 : lo;
        bhi[j] = (go && !less) ? mid : hi;
      }
    }
    float res[4];
#pragma unroll
    for (int j = 0; j < 4; j++) {
      int f = f0 + j;
      while (blo[j] < bhi[j]) {
        int mid = (blo[j] + bhi[j]) >> 1;
        if (qs[qoff(mid, f)] < xa[j]) blo[j] = mid + 1; else bhi[j] = mid;
      }
      int cnt = blo[j];
      int idx = min(max(cnt, 1), QN - 1) - 1;
      float lo = qs[qoff(idx, f)];
      float hi = qs[qoff(idx + 1, f)];
      float diff = hi - lo;
      float interp = (diff == 0.0f) ? 0.5f : __fdividef(xa[j] - lo, diff);
      float y = ((float)idx + interp) * 0.001f;
      y = fminf(fmaxf(y, 0.0f), 1.0f);
      res[j] = probit100(y);
    }
    int row = (it << 7) + rowo;
    *(float4*)(out + ((size_t)row << 5) + f0) =
        make_float4(res[0], res[1], res[2], res[3]);
    xv = xn;
    it = itn;
  }
}
// ===========================================================================

extern "C" void kernel_launch(void* const* d_in, const int* in_sizes, int n_in,
                              void* d_out, int out_size, void* d_ws, size_t ws_size,
                              hipStream_t stream) {
  const float* x = (const float*)d_in[0];
  const float* q = (const float*)d_in[1];
  float* out = (float*)d_out;
  int n = in_sizes[0];
  int nrows = n / NF;

  if (ws_size >= (size_t)TBL_BYTES) {
    float* tbl = (float*)d_ws;
    build_kernel<<<(TBL_FLOATS + 255) / 256, 256, 0, stream>>>(q, tbl);
    hipFuncSetAttribute((const void*)qp_main,
                        hipFuncAttributeMaxDynamicSharedMemorySize, TBL_BYTES);
    qp_main<<<dim3(256), dim3(1024), TBL_BYTES, stream>>>(x, q, tbl, out, nrows);
  } else {
    hipFuncSetAttribute((const void*)qp_kernel,
                        hipFuncAttributeMaxDynamicSharedMemorySize, LDS_TOTAL);
    qp_kernel<<<dim3(256), dim3(1024), LDS_TOTAL, stream>>>(x, q, out, nrows);
  }
}